// Round 1
// baseline (298.546 us; speedup 1.0000x reference)
//
#include <hip/hip_runtime.h>
#include <math.h>

#define PI_F 3.14159265358979323846f
#define BB 2
#define LL 1024
#define DD 512
#define NCH 64
#define CHUNK 32
#define NCHUNK (LL/CHUNK)
#define GROWS 16   // rows per GEMM block

__device__ __forceinline__ float dot4(float4 a, float4 b){
    return a.x*b.x + a.y*b.y + a.z*b.z + a.w*b.w;
}

// acc[4][4] += xs(16x512, LDS) @ W[col0+dl, :512]^T  for this thread's
// micro-tile: rows 4*ty..+3 (ty=tid>>6), local cols 4*tx..+3 (tx=tid&63) of 256.
// wt is a 16x256 LDS staging tile; each W element is read from global exactly once.
__device__ __forceinline__ void gemm_16x256_512(
    const float* xs, const float* __restrict__ W, int col0,
    float acc[4][4], float* wt)
{
    const int tid = threadIdx.x;
    const int tx = tid & 63, ty = tid >> 6;
    for (int kt = 0; kt < 512; kt += 16) {
        __syncthreads();   // also orders caller's xs writes before first read
        {
            // thread t stages row d=col0+t, k = kt..kt+15 (64B, half cache line;
            // other half hits L1 next iter). Write transposed: wt[k][d].
            const float4* src = (const float4*)(W + ((size_t)(col0 + tid))*512 + kt);
            #pragma unroll
            for (int i = 0; i < 4; ++i) {
                float4 v = src[i];
                wt[(4*i+0)*256 + tid] = v.x;
                wt[(4*i+1)*256 + tid] = v.y;
                wt[(4*i+2)*256 + tid] = v.z;
                wt[(4*i+3)*256 + tid] = v.w;
            }
        }
        __syncthreads();
        #pragma unroll
        for (int k = 0; k < 16; k += 4) {
            float xrv[4][4];
            #pragma unroll
            for (int r = 0; r < 4; ++r) {   // broadcast ds_read_b128 (wave-uniform addr)
                float4 t4 = *(const float4*)(xs + (4*ty+r)*512 + kt + k);
                xrv[r][0]=t4.x; xrv[r][1]=t4.y; xrv[r][2]=t4.z; xrv[r][3]=t4.w;
            }
            #pragma unroll
            for (int kk = 0; kk < 4; ++kk) {
                float4 wv = *(const float4*)(wt + (k+kk)*256 + 4*tx); // contiguous b128
                #pragma unroll
                for (int r = 0; r < 4; ++r) {
                    acc[r][0] += xrv[r][kk]*wv.x;
                    acc[r][1] += xrv[r][kk]*wv.y;
                    acc[r][2] += xrv[r][kk]*wv.z;
                    acc[r][3] += xrv[r][kk]*wv.w;
                }
            }
        }
    }
}

// ---- K0: gate g, kp/qp phases -> per-row channel weights a[64], R[64] ----
__global__ __launch_bounds__(256) void k0_gates(
    const float* __restrict__ x,
    const float* __restrict__ Wk, const float* __restrict__ bk,
    const float* __restrict__ Wq, const float* __restrict__ bq,
    const float* __restrict__ Wg1, const float* __restrict__ bg1,
    const float* __restrict__ Wg2, const float* __restrict__ bg2,
    const float* __restrict__ set_w, const float* __restrict__ pos_phases,
    const float* __restrict__ pos_weight,
    float* __restrict__ aB, float* __restrict__ RB)
{
    __shared__ float xs[GROWS*512];
    __shared__ float wt[16*256];
    float* gsh = wt;   // alias: gsh lifetime strictly after gemm's last wt read

    const int tid = threadIdx.x;
    const int row0 = blockIdx.x * GROWS;
    {
        const float4* src = (const float4*)(x + (size_t)row0*512);
        float4* dst = (float4*)xs;
        for (int i = tid; i < GROWS*512/4; i += 256) dst[i] = src[i];
    }
    float acc[4][4];
    #pragma unroll
    for (int r=0;r<4;++r){acc[r][0]=0.f;acc[r][1]=0.f;acc[r][2]=0.f;acc[r][3]=0.f;}
    gemm_16x256_512(xs, Wg1, 0, acc, wt);   // h_pre = x @ Wg1^T  (256 cols = all)

    const int tx = tid & 63, ty = tid >> 6;
    float part[4];
    #pragma unroll
    for (int r=0;r<4;++r) part[r]=0.f;
    #pragma unroll
    for (int c=0;c<4;++c) {
        int col = 4*tx + c;
        float w2 = Wg2[col];
        float bb = bg1[col];
        #pragma unroll
        for (int r=0;r<4;++r) {
            float hv = acc[r][c] + bb;
            float ge = 0.5f*hv*(1.f + erff(hv*0.70710678118f));  // exact gelu
            part[r] += ge*w2;
        }
    }
    #pragma unroll
    for (int off=32; off; off>>=1){
        #pragma unroll
        for (int r=0;r<4;++r) part[r] += __shfl_xor(part[r], off, 64);
    }
    __syncthreads();   // all gemm wt reads done before aliased gsh write
    if (tx == 0){
        float b2 = bg2[0];
        #pragma unroll
        for (int r=0;r<4;++r) gsh[4*ty+r] = 1.f/(1.f+expf(-(part[r]+b2)));
    }
    __syncthreads();

    // kp/qp dot per (row=tid>>4, j=tid&15), then fold everything into a/R
    const int rr = tid >> 4, j = tid & 15;
    const float* xrow = xs + rr*512;
    const float* wkr = Wk + (size_t)j*512;
    const float* wqr = Wq + (size_t)j*512;
    float ka = 0.f, qa = 0.f;
    for (int k=0;k<512;k+=4){
        float4 xv = *(const float4*)(xrow+k);
        ka += dot4(xv, *(const float4*)(wkr+k));
        qa += dot4(xv, *(const float4*)(wqr+k));
    }
    float kang = PI_F*tanhf(ka + bk[j]);
    float qang = PI_F*tanhf(qa + bq[j]);
    const int row = row0 + rr;
    const int l = row & (LL-1);
    const float g = gsh[rr];
    float s0=set_w[0], s1=set_w[1], s2=set_w[2], s3=set_w[3];
    float m = fmaxf(fmaxf(s0,s1), fmaxf(s2,s3));
    float e0=expf(s0-m), e1=expf(s1-m), e2=expf(s2-m), e3=expf(s3-m);
    float wsm = (j<4?e0: j<8?e1: j<12?e2: e3) / (e0+e1+e2+e3);
    float spw = 1.f/(1.f+expf(-pos_weight[0]));
    float rnorm = 1.f/(2.f*sqrtf((float)(l+1)));   // 1/sqrt(4*(l+1)); LN makes this nearly
                                                   // invariant, kept exact anyway
    float* arow = aB + (size_t)row*NCH;
    float* Rrow = RB + (size_t)row*NCH;
    arow[j]    = cosf(kang);
    arow[16+j] = sinf(kang);
    float cw = g*wsm*rnorm;
    Rrow[j]    = cw*cosf(qang);
    Rrow[16+j] = cw*sinf(qang);
    float ph = pos_phases[(size_t)l*16 + j];
    float pc = cosf(ph), ps = sinf(ph);
    arow[32+j] = pc; arow[48+j] = ps;
    float cp = (1.f-g)*spw*rnorm;
    Rrow[32+j] = cp*pc; Rrow[48+j] = cp*ps;
}

// ---- K1: Vr = x @ Wv^T + bv ----
__global__ __launch_bounds__(256) void k1_vr(
    const float* __restrict__ x, const float* __restrict__ Wv,
    const float* __restrict__ bv, float* __restrict__ VrB)
{
    __shared__ float xs[GROWS*512];
    __shared__ float wt[16*256];
    const int tid = threadIdx.x;
    const int row0 = blockIdx.x * GROWS;
    const int col0 = blockIdx.y * 256;
    {
        const float4* src = (const float4*)(x + (size_t)row0*512);
        float4* dst = (float4*)xs;
        for (int i = tid; i < GROWS*512/4; i += 256) dst[i] = src[i];
    }
    float acc[4][4];
    #pragma unroll
    for (int r=0;r<4;++r){acc[r][0]=0.f;acc[r][1]=0.f;acc[r][2]=0.f;acc[r][3]=0.f;}
    gemm_16x256_512(xs, Wv, col0, acc, wt);
    const int tx = tid&63, ty = tid>>6;
    #pragma unroll
    for (int r=0;r<4;++r){
        int row = row0 + 4*ty + r;
        int d0 = col0 + 4*tx;
        float4 b4 = *(const float4*)(bv + d0);
        float4 o = make_float4(acc[r][0]+b4.x, acc[r][1]+b4.y,
                               acc[r][2]+b4.z, acc[r][3]+b4.w);
        *(float4*)(VrB + (size_t)row*512 + d0) = o;
    }
}

// ---- K2a: per-chunk partial sums P[b,c,k,d] = sum_{l in chunk} a_k[l]*Vr[l,d] ----
__global__ __launch_bounds__(256) void k2a_chunksum(
    const float* __restrict__ VrB, const float* __restrict__ aB,
    float* __restrict__ P)
{
    const int c = blockIdx.x, b = blockIdx.y;
    const int d = blockIdx.z*256 + threadIdx.x;
    float S[NCH];
    #pragma unroll
    for (int k=0;k<NCH;++k) S[k]=0.f;
    for (int l=0;l<CHUNK;++l){
        const size_t rowi = (size_t)b*LL + (size_t)c*CHUNK + l;
        float v = VrB[rowi*512 + d];
        const float* ar = aB + rowi*NCH;   // wave-uniform -> scalar loads
        #pragma unroll
        for (int k=0;k<NCH;++k) S[k] = fmaf(ar[k], v, S[k]);
    }
    #pragma unroll
    for (int k=0;k<NCH;++k)
        P[(((size_t)b*NCHUNK + c)*NCH + k)*512 + d] = S[k];
}

// ---- K2b: in-place exclusive prefix over chunks ----
__global__ __launch_bounds__(256) void k2b_prefix(float* __restrict__ P)
{
    const int k = blockIdx.x, b = blockIdx.y;
    const int d = blockIdx.z*256 + threadIdx.x;
    float run = 0.f;
    for (int c=0;c<NCHUNK;++c){
        size_t idx = (((size_t)b*NCHUNK + c)*NCH + k)*512 + d;
        float v = P[idx];
        P[idx] = run;
        run += v;
    }
}

// ---- K2c: intra-chunk scan + readout: T[b,l,d] = sum_k R_k * S_k ----
__global__ __launch_bounds__(256) void k2c_scan(
    const float* __restrict__ VrB, const float* __restrict__ aB,
    const float* __restrict__ RB, const float* __restrict__ P,
    float* __restrict__ T)
{
    const int c = blockIdx.x, b = blockIdx.y;
    const int d = blockIdx.z*256 + threadIdx.x;
    float S[NCH];
    #pragma unroll
    for (int k=0;k<NCH;++k)
        S[k] = P[(((size_t)b*NCHUNK + c)*NCH + k)*512 + d];
    for (int l=0;l<CHUNK;++l){
        const size_t rowi = (size_t)b*LL + (size_t)c*CHUNK + l;
        float v = VrB[rowi*512 + d];
        const float* ar = aB + rowi*NCH;   // wave-uniform -> scalar loads
        const float* rw = RB + rowi*NCH;
        float a0=0.f,a1=0.f,a2=0.f,a3=0.f;  // 4-way split breaks dep chain
        #pragma unroll
        for (int k=0;k<NCH;k+=4){
            S[k]   = fmaf(ar[k],   v, S[k]);   a0 = fmaf(rw[k],   S[k],   a0);
            S[k+1] = fmaf(ar[k+1], v, S[k+1]); a1 = fmaf(rw[k+1], S[k+1], a1);
            S[k+2] = fmaf(ar[k+2], v, S[k+2]); a2 = fmaf(rw[k+2], S[k+2], a2);
            S[k+3] = fmaf(ar[k+3], v, S[k+3]); a3 = fmaf(rw[k+3], S[k+3], a3);
        }
        T[rowi*512 + d] = (a0+a1)+(a2+a3);
    }
}

// ---- K3: LayerNorm(T) -> @ Wo^T + bo + x ----
__global__ __launch_bounds__(256) void k3_out(
    const float* __restrict__ T, const float* __restrict__ x,
    const float* __restrict__ ln_g, const float* __restrict__ ln_b,
    const float* __restrict__ Wo, const float* __restrict__ bo,
    float* __restrict__ out)
{
    __shared__ float ts[GROWS*512];
    __shared__ float wt[16*256];
    float* mus  = wt;        // alias: stats lifetime strictly before gemm staging
    float* rsds = wt + 16;
    const int tid = threadIdx.x;
    const int row0 = blockIdx.x * GROWS;
    const int col0 = blockIdx.y * 256;
    {
        const float4* src = (const float4*)(T + (size_t)row0*512);
        float4* dst = (float4*)ts;
        for (int i = tid; i < GROWS*512/4; i += 256) dst[i] = src[i];
    }
    __syncthreads();
    {
        const int sr = tid >> 4, sl = tid & 15;   // 16 lanes per row
        float s=0.f, sq=0.f;
        for (int i=0;i<32;++i){
            float v = ts[sr*512 + sl + 16*i];
            s += v; sq += v*v;
        }
        #pragma unroll
        for (int off=8; off; off>>=1){
            s  += __shfl_xor(s,  off, 16);
            sq += __shfl_xor(sq, off, 16);
        }
        if (sl==0){
            float mu = s*(1.f/512.f);
            float var = sq*(1.f/512.f) - mu*mu;   // biased var, matches reference
            mus[sr] = mu;
            rsds[sr] = rsqrtf(var + 1e-5f);
        }
    }
    __syncthreads();
    for (int i = tid; i < GROWS*512; i += 256){
        int rr2 = i >> 9, dd = i & 511;
        ts[i] = (ts[i] - mus[rr2])*rsds[rr2]*ln_g[dd] + ln_b[dd];
    }
    // gemm's leading __syncthreads orders normalize writes + mus reads vs wt staging
    float acc[4][4];
    #pragma unroll
    for (int r=0;r<4;++r){acc[r][0]=0.f;acc[r][1]=0.f;acc[r][2]=0.f;acc[r][3]=0.f;}
    gemm_16x256_512(ts, Wo, col0, acc, wt);
    const int tx = tid&63, ty = tid>>6;
    #pragma unroll
    for (int r=0;r<4;++r){
        int row = row0 + 4*ty + r;
        int d0 = col0 + 4*tx;
        float4 x4 = *(const float4*)(x + (size_t)row*512 + d0);
        float4 b4 = *(const float4*)(bo + d0);
        float4 o = make_float4(x4.x+acc[r][0]+b4.x, x4.y+acc[r][1]+b4.y,
                               x4.z+acc[r][2]+b4.z, x4.w+acc[r][3]+b4.w);
        *(float4*)(out + (size_t)row*512 + d0) = o;
    }
}

extern "C" void kernel_launch(void* const* d_in, const int* in_sizes, int n_in,
                              void* d_out, int out_size, void* d_ws, size_t ws_size,
                              hipStream_t stream) {
    const float* x    = (const float*)d_in[0];
    const float* Wk   = (const float*)d_in[1];
    const float* bk   = (const float*)d_in[2];
    const float* Wq   = (const float*)d_in[3];
    const float* bq   = (const float*)d_in[4];
    const float* Wv   = (const float*)d_in[5];
    const float* bv   = (const float*)d_in[6];
    const float* ln_g = (const float*)d_in[7];
    const float* ln_b = (const float*)d_in[8];
    const float* Wo   = (const float*)d_in[9];
    const float* bo   = (const float*)d_in[10];
    const float* set_w      = (const float*)d_in[11];
    const float* pos_phases = (const float*)d_in[12];
    const float* pos_weight = (const float*)d_in[13];
    const float* Wg1  = (const float*)d_in[14];
    const float* bg1  = (const float*)d_in[15];
    const float* Wg2  = (const float*)d_in[16];
    const float* bg2  = (const float*)d_in[17];
    float* out = (float*)d_out;

    // workspace layout (floats): ~17.8 MB total
    float* ws  = (float*)d_ws;
    float* VrB = ws;                                   // B*L*D        = 1048576
    float* aB  = VrB + (size_t)BB*LL*DD;               // B*L*64       =  131072
    float* RB  = aB  + (size_t)BB*LL*NCH;              // B*L*64       =  131072
    float* P   = RB  + (size_t)BB*LL*NCH;              // B*NC*64*D    = 2097152
    float* T   = P   + (size_t)BB*NCHUNK*NCH*DD;       // B*L*D        = 1048576

    k0_gates<<<dim3(BB*LL/GROWS), 256, 0, stream>>>(
        x, Wk, bk, Wq, bq, Wg1, bg1, Wg2, bg2, set_w, pos_phases, pos_weight, aB, RB);
    k1_vr<<<dim3(BB*LL/GROWS, 2), 256, 0, stream>>>(x, Wv, bv, VrB);
    k2a_chunksum<<<dim3(NCHUNK, BB, 2), 256, 0, stream>>>(VrB, aB, P);
    k2b_prefix<<<dim3(NCH, BB, 2), 256, 0, stream>>>(P);
    k2c_scan<<<dim3(NCHUNK, BB, 2), 256, 0, stream>>>(VrB, aB, RB, P, T);
    k3_out<<<dim3(BB*LL/GROWS, 2), 256, 0, stream>>>(T, x, ln_g, ln_b, Wo, bo, out);
}

// Round 2
// 246.566 us; speedup vs baseline: 1.2108x; 1.2108x over previous
//
#include <hip/hip_runtime.h>
#include <math.h>

#define PI_F 3.14159265358979323846f
#define BB 2
#define LL 1024
#define DD 512
#define NCH 64
#define CHUNK 32
#define NCHUNK (LL/CHUNK)
#define WT 1344          // Wt column stride (floats); valid cols = 1312
#define YN 896           // Y column stride = 7 col-tiles of 128

// Wt column map: [0,512)=Wv -> Vr, [512,768)=Wg1 -> h, [768,784)=Wk -> kp,
//                [784,800)=Wq -> qp, [800,1312)=Wo.
// Y (2048 x 896) holds the fused GEMM1 output for cols [0,896) of Wt
// (cols 800..896 are valid-but-unused Wo outputs from tile padding).

// ---- prep: transpose+concat weights into Wt[k][n], build bcat[n] ----
__global__ __launch_bounds__(256) void k_prep(
    const float* __restrict__ Wv, const float* __restrict__ Wg1,
    const float* __restrict__ Wk, const float* __restrict__ Wq,
    const float* __restrict__ Wo,
    const float* __restrict__ bv, const float* __restrict__ bg1,
    const float* __restrict__ bk, const float* __restrict__ bq,
    const float* __restrict__ bo,
    float* __restrict__ Wt_, float* __restrict__ bcat)
{
    __shared__ float t[32][33];
    const int n0 = blockIdx.x*32, k0 = blockIdx.y*32;
    const int c = threadIdx.x & 31, r = threadIdx.x >> 5;
    #pragma unroll
    for (int i=0;i<4;++i){
        int n = n0 + r + 8*i;
        const float* src = (n<512) ? Wv  + (size_t)n*512
                         : (n<768) ? Wg1 + (size_t)(n-512)*512
                         : (n<784) ? Wk  + (size_t)(n-768)*512
                         : (n<800) ? Wq  + (size_t)(n-784)*512
                                   : Wo  + (size_t)(n-800)*512;
        t[r+8*i][c] = src[k0 + c];            // coalesced in k
    }
    __syncthreads();
    #pragma unroll
    for (int i=0;i<4;++i)
        Wt_[(size_t)(k0 + r + 8*i)*WT + n0 + c] = t[c][r+8*i];  // coalesced in n
    if (blockIdx.y==0 && threadIdx.x < 32){
        int n = n0 + threadIdx.x;
        bcat[n] = (n<512)?bv[n] : (n<768)?bg1[n-512] : (n<784)?bk[n-768]
                : (n<800)?bq[n-784] : bo[n-800];
    }
}

// ---- barrier-free streaming GEMM core: 16 rows (LDS) x 128 cols (streamed W) ----
// thread: tx=tid&31 -> 4 cols, ty=tid>>5 -> 2 rows. No barriers in K-loop ->
// compiler software-pipelines the W loads with fine-grained vmcnt.
__device__ __forceinline__ void stream_gemm(
    const float* xs, const float* __restrict__ Wt_, int c, int r0, float acc[2][4])
{
    #pragma unroll 4
    for (int k=0;k<512;k+=4){
        float4 wv[4];
        #pragma unroll
        for (int kk=0;kk<4;++kk)
            wv[kk] = *(const float4*)(Wt_ + (size_t)(k+kk)*WT + c);
        float4 xa = *(const float4*)(xs + r0*512 + k);        // 2-way LDS alias: free
        float4 xb = *(const float4*)(xs + (r0+1)*512 + k);
        float xv[2][4] = {{xa.x,xa.y,xa.z,xa.w},{xb.x,xb.y,xb.z,xb.w}};
        #pragma unroll
        for (int kk=0;kk<4;++kk){
            const float* wf = (const float*)&wv[kk];
            #pragma unroll
            for (int r=0;r<2;++r)
                #pragma unroll
                for (int q=0;q<4;++q)
                    acc[r][q] = fmaf(xv[r][kk], wf[q], acc[r][q]);
        }
    }
}

// ---- GEMM1: Y[0..896) = x @ Wt + bcat  (Vr | h | kp | qp | pad) ----
__global__ __launch_bounds__(256) void kg1(
    const float* __restrict__ x, const float* __restrict__ Wt_,
    const float* __restrict__ bcat, float* __restrict__ Y)
{
    __shared__ float xs[16*512];
    const int tid = threadIdx.x;
    const int row0 = blockIdx.x*16, col0 = blockIdx.y*128;
    {
        const float4* src = (const float4*)(x + (size_t)row0*512);
        float4* dst = (float4*)xs;
        #pragma unroll
        for (int i=0;i<8;++i) dst[tid + 256*i] = src[tid + 256*i];
    }
    __syncthreads();
    const int tx = tid&31, ty = tid>>5;
    const int r0 = 2*ty, c = col0 + 4*tx;
    float acc[2][4] = {};
    stream_gemm(xs, Wt_, c, r0, acc);
    float4 b4 = *(const float4*)(bcat + c);
    #pragma unroll
    for (int r=0;r<2;++r){
        int row = row0 + r0 + r;
        float4 o = make_float4(acc[r][0]+b4.x, acc[r][1]+b4.y,
                               acc[r][2]+b4.z, acc[r][3]+b4.w);
        *(float4*)(Y + (size_t)row*YN + c) = o;
    }
}

// ---- activations: gate g + phases -> a[64], R[64] per row ----
__global__ __launch_bounds__(256) void k_act(
    const float* __restrict__ Y, const float* __restrict__ Wg2,
    const float* __restrict__ bg2, const float* __restrict__ set_w,
    const float* __restrict__ pos_phases, const float* __restrict__ pos_weight,
    float* __restrict__ aB, float* __restrict__ RB)
{
    const int tid = threadIdx.x, lane = tid & 63, w = tid >> 6;
    const int row0 = blockIdx.x * 8;
    float s0=set_w[0], s1=set_w[1], s2=set_w[2], s3=set_w[3];
    float m = fmaxf(fmaxf(s0,s1), fmaxf(s2,s3));
    float e0=expf(s0-m), e1=expf(s1-m), e2=expf(s2-m), e3=expf(s3-m);
    float esum = e0+e1+e2+e3;
    float spw = 1.f/(1.f+expf(-pos_weight[0]));
    float b2 = bg2[0];
    #pragma unroll
    for (int rr=0;rr<2;++rr){
        int row = row0 + w + 4*rr;
        const float* yrow = Y + (size_t)row*YN;
        float hs = 0.f;
        #pragma unroll
        for (int i=0;i<4;++i){
            float hv = yrow[512 + lane + 64*i];               // bg1 already added
            float ge = 0.5f*hv*(1.f + erff(hv*0.70710678118f));
            hs += ge * Wg2[lane + 64*i];
        }
        #pragma unroll
        for (int off=32; off; off>>=1) hs += __shfl_xor(hs, off, 64);
        float g = 1.f/(1.f+expf(-(hs + b2)));
        if (lane < 16){
            int j = lane;
            int l = row & (LL-1);
            float kang = PI_F*tanhf(yrow[768 + j]);           // bk already added
            float qang = PI_F*tanhf(yrow[784 + j]);
            float wsm = (j<4?e0: j<8?e1: j<12?e2: e3) / esum;
            float rnorm = 1.f/(2.f*sqrtf((float)(l+1)));      // 1/sqrt(4(l+1))
            float* arow = aB + (size_t)row*NCH;
            float* Rrow = RB + (size_t)row*NCH;
            arow[j]    = cosf(kang);
            arow[16+j] = sinf(kang);
            float cw = g*wsm*rnorm;
            Rrow[j]    = cw*cosf(qang);
            Rrow[16+j] = cw*sinf(qang);
            float ph = pos_phases[(size_t)l*16 + j];
            float pc = cosf(ph), ps = sinf(ph);
            arow[32+j] = pc; arow[48+j] = ps;
            float cp = (1.f-g)*spw*rnorm;
            Rrow[32+j] = cp*pc; Rrow[48+j] = cp*ps;
        }
    }
}

// ---- K2a: per-chunk sums P[b,c,k,d] ----
__global__ __launch_bounds__(256) void k2a_chunksum(
    const float* __restrict__ Y, const float* __restrict__ aB,
    float* __restrict__ P)
{
    const int c = blockIdx.x, b = blockIdx.y;
    const int d = blockIdx.z*256 + threadIdx.x;
    float S[NCH];
    #pragma unroll
    for (int k=0;k<NCH;++k) S[k]=0.f;
    for (int l=0;l<CHUNK;++l){
        const size_t rowi = (size_t)b*LL + (size_t)c*CHUNK + l;
        float v = Y[rowi*YN + d];                 // Vr lives in Y cols [0,512)
        const float* ar = aB + rowi*NCH;          // wave-uniform -> scalar loads
        #pragma unroll
        for (int k=0;k<NCH;++k) S[k] = fmaf(ar[k], v, S[k]);
    }
    #pragma unroll
    for (int k=0;k<NCH;++k)
        P[(((size_t)b*NCHUNK + c)*NCH + k)*512 + d] = S[k];
}

// ---- K2b: exclusive prefix over chunks (float4 over d) ----
__global__ __launch_bounds__(128) void k2b_prefix(float* __restrict__ P)
{
    const int k = blockIdx.x, b = blockIdx.y;
    const int d4 = threadIdx.x;
    float4 run = make_float4(0.f,0.f,0.f,0.f);
    for (int c=0;c<NCHUNK;++c){
        float4* p = (float4*)(P + (((size_t)b*NCHUNK + c)*NCH + k)*512) + d4;
        float4 v = *p;
        *p = run;
        run.x+=v.x; run.y+=v.y; run.z+=v.z; run.w+=v.w;
    }
}

// ---- K2c: intra-chunk scan + readout -> T ----
__global__ __launch_bounds__(256) void k2c_scan(
    const float* __restrict__ Y, const float* __restrict__ aB,
    const float* __restrict__ RB, const float* __restrict__ P,
    float* __restrict__ T_)
{
    const int c = blockIdx.x, b = blockIdx.y;
    const int d = blockIdx.z*256 + threadIdx.x;
    float S[NCH];
    #pragma unroll
    for (int k=0;k<NCH;++k)
        S[k] = P[(((size_t)b*NCHUNK + c)*NCH + k)*512 + d];
    for (int l=0;l<CHUNK;++l){
        const size_t rowi = (size_t)b*LL + (size_t)c*CHUNK + l;
        float v = Y[rowi*YN + d];
        const float* ar = aB + rowi*NCH;
        const float* rw = RB + rowi*NCH;
        float a0=0.f,a1=0.f,a2=0.f,a3=0.f;
        #pragma unroll
        for (int k=0;k<NCH;k+=4){
            S[k]   = fmaf(ar[k],   v, S[k]);   a0 = fmaf(rw[k],   S[k],   a0);
            S[k+1] = fmaf(ar[k+1], v, S[k+1]); a1 = fmaf(rw[k+1], S[k+1], a1);
            S[k+2] = fmaf(ar[k+2], v, S[k+2]); a2 = fmaf(rw[k+2], S[k+2], a2);
            S[k+3] = fmaf(ar[k+3], v, S[k+3]); a3 = fmaf(rw[k+3], S[k+3], a3);
        }
        T_[rowi*512 + d] = (a0+a1)+(a2+a3);
    }
}

// ---- GEMM2: out = x + LN(T) @ Wo^T + bo ----
__global__ __launch_bounds__(256) void kg2(
    const float* __restrict__ T_, const float* __restrict__ x,
    const float* __restrict__ ln_g, const float* __restrict__ ln_b,
    const float* __restrict__ Wt_, const float* __restrict__ bcat,
    float* __restrict__ out)
{
    __shared__ float ts[16*512];
    __shared__ float mus[16], rsds[16];
    const int tid = threadIdx.x;
    const int row0 = blockIdx.x*16, col0 = blockIdx.y*128;
    {
        const float4* src = (const float4*)(T_ + (size_t)row0*512);
        float4* dst = (float4*)ts;
        #pragma unroll
        for (int i=0;i<8;++i) dst[tid + 256*i] = src[tid + 256*i];
    }
    __syncthreads();
    {
        const int sr = tid >> 4, sl = tid & 15;
        float s=0.f, sq=0.f;
        #pragma unroll 8
        for (int i=0;i<32;++i){
            float v = ts[sr*512 + sl + 16*i];
            s += v; sq += v*v;
        }
        #pragma unroll
        for (int off=8; off; off>>=1){
            s  += __shfl_xor(s,  off, 16);
            sq += __shfl_xor(sq, off, 16);
        }
        if (sl==0){
            float mu = s*(1.f/512.f);
            float var = sq*(1.f/512.f) - mu*mu;
            mus[sr] = mu;
            rsds[sr] = rsqrtf(var + 1e-5f);
        }
    }
    __syncthreads();
    for (int i = tid; i < 16*512; i += 256){
        int rr = i >> 9, dd = i & 511;
        ts[i] = (ts[i] - mus[rr])*rsds[rr]*ln_g[dd] + ln_b[dd];
    }
    __syncthreads();
    const int tx = tid&31, ty = tid>>5;
    const int r0 = 2*ty, c = 800 + col0 + 4*tx;   // Wo region of Wt
    float acc[2][4] = {};
    stream_gemm(ts, Wt_, c, r0, acc);
    float4 b4 = *(const float4*)(bcat + c);
    const int d0 = col0 + 4*tx;
    #pragma unroll
    for (int r=0;r<2;++r){
        int row = row0 + r0 + r;
        float4 x4 = *(const float4*)(x + (size_t)row*512 + d0);
        float4 o = make_float4(x4.x+acc[r][0]+b4.x, x4.y+acc[r][1]+b4.y,
                               x4.z+acc[r][2]+b4.z, x4.w+acc[r][3]+b4.w);
        *(float4*)(out + (size_t)row*512 + d0) = o;
    }
}

extern "C" void kernel_launch(void* const* d_in, const int* in_sizes, int n_in,
                              void* d_out, int out_size, void* d_ws, size_t ws_size,
                              hipStream_t stream) {
    const float* x    = (const float*)d_in[0];
    const float* Wk   = (const float*)d_in[1];
    const float* bk   = (const float*)d_in[2];
    const float* Wq   = (const float*)d_in[3];
    const float* bq   = (const float*)d_in[4];
    const float* Wv   = (const float*)d_in[5];
    const float* bv   = (const float*)d_in[6];
    const float* ln_g = (const float*)d_in[7];
    const float* ln_b = (const float*)d_in[8];
    const float* Wo   = (const float*)d_in[9];
    const float* bo   = (const float*)d_in[10];
    const float* set_w      = (const float*)d_in[11];
    const float* pos_phases = (const float*)d_in[12];
    const float* pos_weight = (const float*)d_in[13];
    const float* Wg1  = (const float*)d_in[14];
    const float* bg1  = (const float*)d_in[15];
    const float* Wg2  = (const float*)d_in[16];
    const float* bg2  = (const float*)d_in[17];
    float* out = (float*)d_out;

    // workspace (floats): 688128 + 1344 + 1835008 + 131072 + 131072 + 2097152
    //                     + 1048576 = 5,932,352 floats ~= 23.7 MB
    float* ws   = (float*)d_ws;
    float* Wt_  = ws;
    float* bcat = Wt_  + (size_t)512*WT;
    float* Y    = bcat + WT;
    float* aB   = Y    + (size_t)BB*LL*YN;
    float* RB   = aB   + (size_t)BB*LL*NCH;
    float* P    = RB   + (size_t)BB*LL*NCH;
    float* T_   = P    + (size_t)BB*NCHUNK*NCH*DD;

    k_prep<<<dim3(41,16), 256, 0, stream>>>(Wv,Wg1,Wk,Wq,Wo, bv,bg1,bk,bq,bo, Wt_, bcat);
    kg1<<<dim3(BB*LL/16, 7), 256, 0, stream>>>(x, Wt_, bcat, Y);
    k_act<<<dim3(BB*LL/8), 256, 0, stream>>>(Y, Wg2, bg2, set_w, pos_phases, pos_weight, aB, RB);
    k2a_chunksum<<<dim3(NCHUNK, BB, 2), 256, 0, stream>>>(Y, aB, P);
    k2b_prefix<<<dim3(NCH, BB), 128, 0, stream>>>(P);
    k2c_scan<<<dim3(NCHUNK, BB, 2), 256, 0, stream>>>(Y, aB, RB, P, T_);
    kg2<<<dim3(BB*LL/16, 4), 256, 0, stream>>>(T_, x, ln_g, ln_b, Wt_, bcat, out);
}

// Round 3
// 167.112 us; speedup vs baseline: 1.7865x; 1.4754x over previous
//
#include <hip/hip_runtime.h>
#include <math.h>

#define PI_F 3.14159265358979323846f
#define BB 2
#define LL 1024
#define DD 512
#define NCH 64
#define CHUNK 32
#define NCHUNK (LL/CHUNK)
#define YN 896           // Y column stride (fp32 GEMM1 output)
#define NW 1408          // Wb rows: 512 Wv | 256 Wg1 | 16 Wk | 16 Wq | 96 pad0 | 512 Wo

typedef __attribute__((ext_vector_type(8))) short short8;
typedef __attribute__((ext_vector_type(4))) float floatx4;
typedef const __attribute__((address_space(1))) unsigned int cgu32;
typedef __attribute__((address_space(3))) unsigned int lu32;

__device__ __forceinline__ unsigned short f2bf(float f){
    unsigned u = __float_as_uint(f);
    unsigned r = (u + 0x7fff + ((u >> 16) & 1)) >> 16;   // RNE
    return (unsigned short)r;
}

// ---- prep: weights -> bf16 Wb[n][k] (k contiguous), bcat fp32 ----
__global__ __launch_bounds__(128) void k_prep(
    const float* __restrict__ Wv, const float* __restrict__ Wg1,
    const float* __restrict__ Wk, const float* __restrict__ Wq,
    const float* __restrict__ Wo,
    const float* __restrict__ bv, const float* __restrict__ bg1,
    const float* __restrict__ bk, const float* __restrict__ bq,
    const float* __restrict__ bo,
    unsigned short* __restrict__ Wb, float* __restrict__ bcat)
{
    const int n = blockIdx.x, tid = threadIdx.x;
    const float* src = (n<512) ? Wv  + (size_t)n*512
                     : (n<768) ? Wg1 + (size_t)(n-512)*512
                     : (n<784) ? Wk  + (size_t)(n-768)*512
                     : (n<800) ? Wq  + (size_t)(n-784)*512
                     : (n<896) ? (const float*)0
                               : Wo  + (size_t)(n-896)*512;
    float4 v = make_float4(0.f,0.f,0.f,0.f);
    if (src) v = ((const float4*)src)[tid];
    ushort4 o; o.x=f2bf(v.x); o.y=f2bf(v.y); o.z=f2bf(v.z); o.w=f2bf(v.w);
    ((ushort4*)(Wb + (size_t)n*512))[tid] = o;
    if (tid == 0)
        bcat[n] = (n<512)?bv[n] : (n<768)?bg1[n-512] : (n<784)?bk[n-768]
                : (n<800)?bq[n-784] : (n<896)?0.f : bo[n-896];
}

// ---- x -> bf16 ----
__global__ __launch_bounds__(256) void k_xb(
    const float* __restrict__ x, unsigned short* __restrict__ xb)
{
    const int i = blockIdx.x*256 + threadIdx.x;     // float4 index
    float4 v = ((const float4*)x)[i];
    ushort4 o; o.x=f2bf(v.x); o.y=f2bf(v.y); o.z=f2bf(v.z); o.w=f2bf(v.w);
    ((ushort4*)xb)[i] = o;
}

// ---- MFMA 64x64x512 tile core: C = A(64xK) * B(64xK)^T, bf16 in, fp32 acc.
// LDS layout XOR-swizzled per row (blk' = blk ^ (row&7)) so fragment
// ds_read_b128 is 2-way per quad (free) while global_load_lds keeps its
// mandatory lane-contiguous dest. Staging: wave w stages rows 16w..16w+15
// of both tiles (2 insts each, 1KB/inst).
__device__ __forceinline__ void gemm64x64(
    const unsigned short* Ag, const unsigned short* Bg,
    short* As, short* Bs, int tid, floatx4 acc[2][2])
{
    const int lane = tid & 63, w = tid >> 6;
    const int wm = w & 1, wn = w >> 1;
    const int q = lane >> 4, m15 = lane & 15;
    for (int kt = 0; kt < 512; kt += 64) {
        __syncthreads();                       // prior iter's frag reads done
        #pragma unroll
        for (int i = 0; i < 2; ++i) {
            const int rowbase = (w*2 + i) * 8;
            const int r  = rowbase + (lane >> 3);
            const int gb = (lane & 7) ^ (r & 7);
            const unsigned short* ga = Ag + (size_t)r*512 + kt + gb*8;
            const unsigned short* gbp = Bg + (size_t)r*512 + kt + gb*8;
            __builtin_amdgcn_global_load_lds((cgu32*)(const void*)ga,
                                             (lu32*)(As + rowbase*64), 16, 0, 0);
            __builtin_amdgcn_global_load_lds((cgu32*)(const void*)gbp,
                                             (lu32*)(Bs + rowbase*64), 16, 0, 0);
        }
        __syncthreads();                       // compiler drains vmcnt here
        #pragma unroll
        for (int k32 = 0; k32 < 64; k32 += 32) {
            short8 af[2], bf[2];
            #pragma unroll
            for (int t = 0; t < 2; ++t) {
                const int ra  = 32*wm + 16*t + m15;
                const int sba = ((k32>>3) + q) ^ (ra & 7);
                af[t] = *(const short8*)(As + ra*64 + sba*8);
                const int rb  = 32*wn + 16*t + m15;
                const int sbb = ((k32>>3) + q) ^ (rb & 7);
                bf[t] = *(const short8*)(Bs + rb*64 + sbb*8);
            }
            #pragma unroll
            for (int mt = 0; mt < 2; ++mt)
                #pragma unroll
                for (int nt = 0; nt < 2; ++nt)
                    acc[mt][nt] = __builtin_amdgcn_mfma_f32_16x16x32_bf16(
                        af[mt], bf[nt], acc[mt][nt], 0, 0, 0);
        }
    }
}

// ---- GEMM1: Y[2048][896] = xb @ Wb[0:896]^T + bcat (fp32 out) ----
__global__ __launch_bounds__(256) void kg1(
    const unsigned short* __restrict__ xb, const unsigned short* __restrict__ Wb,
    const float* __restrict__ bcat, float* __restrict__ Y)
{
    __shared__ short As[64*64], Bs[64*64];
    const int tid = threadIdx.x;
    const int row0 = blockIdx.x*64, n0 = blockIdx.y*64;
    floatx4 acc[2][2];
    #pragma unroll
    for (int mt=0;mt<2;++mt)
        #pragma unroll
        for (int nt=0;nt<2;++nt) acc[mt][nt] = (floatx4){0.f,0.f,0.f,0.f};
    gemm64x64(xb + (size_t)row0*512, Wb + (size_t)n0*512, As, Bs, tid, acc);
    const int lane = tid & 63, w = tid >> 6;
    const int wm = w & 1, wn = w >> 1, q = lane >> 4, m15 = lane & 15;
    #pragma unroll
    for (int mt=0;mt<2;++mt)
        #pragma unroll
        for (int nt=0;nt<2;++nt){
            const int n = n0 + 32*wn + 16*nt + m15;
            const float b = bcat[n];
            #pragma unroll
            for (int reg=0;reg<4;++reg){
                const int m = row0 + 32*wm + 16*mt + q*4 + reg;
                Y[(size_t)m*YN + n] = acc[mt][nt][reg] + b;
            }
        }
}

// ---- activations: gate g + phases -> a[64], R[64] per row ----
__global__ __launch_bounds__(256) void k_act(
    const float* __restrict__ Y, const float* __restrict__ Wg2,
    const float* __restrict__ bg2, const float* __restrict__ set_w,
    const float* __restrict__ pos_phases, const float* __restrict__ pos_weight,
    float* __restrict__ aB, float* __restrict__ RB)
{
    const int tid = threadIdx.x, lane = tid & 63, w = tid >> 6;
    const int row0 = blockIdx.x * 8;
    float s0=set_w[0], s1=set_w[1], s2=set_w[2], s3=set_w[3];
    float m = fmaxf(fmaxf(s0,s1), fmaxf(s2,s3));
    float e0=expf(s0-m), e1=expf(s1-m), e2=expf(s2-m), e3=expf(s3-m);
    float esum = e0+e1+e2+e3;
    float spw = 1.f/(1.f+expf(-pos_weight[0]));
    float b2 = bg2[0];
    #pragma unroll
    for (int rr=0;rr<2;++rr){
        int row = row0 + w + 4*rr;
        const float* yrow = Y + (size_t)row*YN;
        float hs = 0.f;
        #pragma unroll
        for (int i=0;i<4;++i){
            float hv = yrow[512 + lane + 64*i];               // bg1 already added
            float ge = 0.5f*hv*(1.f + erff(hv*0.70710678118f));
            hs += ge * Wg2[lane + 64*i];
        }
        #pragma unroll
        for (int off=32; off; off>>=1) hs += __shfl_xor(hs, off, 64);
        float g = 1.f/(1.f+expf(-(hs + b2)));
        if (lane < 16){
            int j = lane;
            int l = row & (LL-1);
            float kang = PI_F*tanhf(yrow[768 + j]);           // bk already added
            float qang = PI_F*tanhf(yrow[784 + j]);
            float wsm = (j<4?e0: j<8?e1: j<12?e2: e3) / esum;
            float rnorm = 1.f/(2.f*sqrtf((float)(l+1)));      // 1/sqrt(4(l+1))
            float* arow = aB + (size_t)row*NCH;
            float* Rrow = RB + (size_t)row*NCH;
            arow[j]    = cosf(kang);
            arow[16+j] = sinf(kang);
            float cw = g*wsm*rnorm;
            Rrow[j]    = cw*cosf(qang);
            Rrow[16+j] = cw*sinf(qang);
            float ph = pos_phases[(size_t)l*16 + j];
            float pc = cosf(ph), ps = sinf(ph);
            arow[32+j] = pc; arow[48+j] = ps;
            float cp = (1.f-g)*spw*rnorm;
            Rrow[32+j] = cp*pc; Rrow[48+j] = cp*ps;
        }
    }
}

// ---- K2a: per-chunk sums P[b,c,k,d] ----
__global__ __launch_bounds__(128) void k2a_chunksum(
    const float* __restrict__ Y, const float* __restrict__ aB,
    float* __restrict__ P)
{
    const int c = blockIdx.x, b = blockIdx.y;
    const int d = blockIdx.z*128 + threadIdx.x;
    float S[NCH];
    #pragma unroll
    for (int k=0;k<NCH;++k) S[k]=0.f;
    for (int l=0;l<CHUNK;++l){
        const size_t rowi = (size_t)b*LL + (size_t)c*CHUNK + l;
        float v = Y[rowi*YN + d];                 // Vr = Y cols [0,512)
        const float* ar = aB + rowi*NCH;          // wave-uniform -> scalar loads
        #pragma unroll
        for (int k=0;k<NCH;++k) S[k] = fmaf(ar[k], v, S[k]);
    }
    #pragma unroll
    for (int k=0;k<NCH;++k)
        P[(((size_t)b*NCHUNK + c)*NCH + k)*512 + d] = S[k];
}

// ---- K2b: exclusive prefix over chunks ----
__global__ __launch_bounds__(128) void k2b_prefix(float* __restrict__ P)
{
    const int k = blockIdx.x, b = blockIdx.y;
    const int d = blockIdx.z*128 + threadIdx.x;
    float run = 0.f;
    for (int c=0;c<NCHUNK;++c){
        size_t idx = (((size_t)b*NCHUNK + c)*NCH + k)*512 + d;
        float v = P[idx];
        P[idx] = run;
        run += v;
    }
}

// ---- K2c: intra-chunk scan + readout -> T ----
__global__ __launch_bounds__(128) void k2c_scan(
    const float* __restrict__ Y, const float* __restrict__ aB,
    const float* __restrict__ RB, const float* __restrict__ P,
    float* __restrict__ T_)
{
    const int c = blockIdx.x, b = blockIdx.y;
    const int d = blockIdx.z*128 + threadIdx.x;
    float S[NCH];
    #pragma unroll
    for (int k=0;k<NCH;++k)
        S[k] = P[(((size_t)b*NCHUNK + c)*NCH + k)*512 + d];
    for (int l=0;l<CHUNK;++l){
        const size_t rowi = (size_t)b*LL + (size_t)c*CHUNK + l;
        float v = Y[rowi*YN + d];
        const float* ar = aB + rowi*NCH;
        const float* rw = RB + rowi*NCH;
        float a0=0.f,a1=0.f,a2=0.f,a3=0.f;
        #pragma unroll
        for (int k=0;k<NCH;k+=4){
            S[k]   = fmaf(ar[k],   v, S[k]);   a0 = fmaf(rw[k],   S[k],   a0);
            S[k+1] = fmaf(ar[k+1], v, S[k+1]); a1 = fmaf(rw[k+1], S[k+1], a1);
            S[k+2] = fmaf(ar[k+2], v, S[k+2]); a2 = fmaf(rw[k+2], S[k+2], a2);
            S[k+3] = fmaf(ar[k+3], v, S[k+3]); a3 = fmaf(rw[k+3], S[k+3], a3);
        }
        T_[rowi*512 + d] = (a0+a1)+(a2+a3);
    }
}

// ---- LN(T) -> bf16 Tn ----
__global__ __launch_bounds__(256) void k_ln(
    const float* __restrict__ T_, const float* __restrict__ ln_g,
    const float* __restrict__ ln_b, unsigned short* __restrict__ Tn)
{
    const int tid = threadIdx.x, lane = tid & 63;
    const int r = blockIdx.x*4 + (tid >> 6);
    const float4* tr = (const float4*)(T_ + (size_t)r*512);
    float4 v0 = tr[lane], v1 = tr[lane+64];
    float s  = v0.x+v0.y+v0.z+v0.w + v1.x+v1.y+v1.z+v1.w;
    float sq = v0.x*v0.x+v0.y*v0.y+v0.z*v0.z+v0.w*v0.w
             + v1.x*v1.x+v1.y*v1.y+v1.z*v1.z+v1.w*v1.w;
    #pragma unroll
    for (int off=32; off; off>>=1){ s += __shfl_xor(s, off, 64); sq += __shfl_xor(sq, off, 64); }
    float mu  = s*(1.f/512.f);
    float var = sq*(1.f/512.f) - mu*mu;
    float rsd = rsqrtf(var + 1e-5f);
    const float4* g4 = (const float4*)ln_g;
    const float4* b4 = (const float4*)ln_b;
    float4 g0 = g4[lane], g1 = g4[lane+64], bb0 = b4[lane], bb1 = b4[lane+64];
    ushort4 o0, o1;
    o0.x = f2bf((v0.x-mu)*rsd*g0.x + bb0.x);
    o0.y = f2bf((v0.y-mu)*rsd*g0.y + bb0.y);
    o0.z = f2bf((v0.z-mu)*rsd*g0.z + bb0.z);
    o0.w = f2bf((v0.w-mu)*rsd*g0.w + bb0.w);
    o1.x = f2bf((v1.x-mu)*rsd*g1.x + bb1.x);
    o1.y = f2bf((v1.y-mu)*rsd*g1.y + bb1.y);
    o1.z = f2bf((v1.z-mu)*rsd*g1.z + bb1.z);
    o1.w = f2bf((v1.w-mu)*rsd*g1.w + bb1.w);
    ushort4* dst = (ushort4*)(Tn + (size_t)r*512);
    dst[lane] = o0; dst[lane+64] = o1;
}

// ---- GEMM2: out = x + Tn @ Wo^T + bo ----
__global__ __launch_bounds__(256) void kg2(
    const unsigned short* __restrict__ Tn, const unsigned short* __restrict__ Wb,
    const float* __restrict__ bcat, const float* __restrict__ x,
    float* __restrict__ out)
{
    __shared__ short As[64*64], Bs[64*64];
    const int tid = threadIdx.x;
    const int row0 = blockIdx.x*64, n0 = blockIdx.y*64;
    floatx4 acc[2][2];
    #pragma unroll
    for (int mt=0;mt<2;++mt)
        #pragma unroll
        for (int nt=0;nt<2;++nt) acc[mt][nt] = (floatx4){0.f,0.f,0.f,0.f};
    gemm64x64(Tn + (size_t)row0*512, Wb + (size_t)(896+n0)*512, As, Bs, tid, acc);
    const int lane = tid & 63, w = tid >> 6;
    const int wm = w & 1, wn = w >> 1, q = lane >> 4, m15 = lane & 15;
    #pragma unroll
    for (int mt=0;mt<2;++mt)
        #pragma unroll
        for (int nt=0;nt<2;++nt){
            const int n = n0 + 32*wn + 16*nt + m15;
            const float b = bcat[896 + n];
            #pragma unroll
            for (int reg=0;reg<4;++reg){
                const int m = row0 + 32*wm + 16*mt + q*4 + reg;
                out[(size_t)m*512 + n] = x[(size_t)m*512 + n] + acc[mt][nt][reg] + b;
            }
        }
}

extern "C" void kernel_launch(void* const* d_in, const int* in_sizes, int n_in,
                              void* d_out, int out_size, void* d_ws, size_t ws_size,
                              hipStream_t stream) {
    const float* x    = (const float*)d_in[0];
    const float* Wk   = (const float*)d_in[1];
    const float* bk   = (const float*)d_in[2];
    const float* Wq   = (const float*)d_in[3];
    const float* bq   = (const float*)d_in[4];
    const float* Wv   = (const float*)d_in[5];
    const float* bv   = (const float*)d_in[6];
    const float* ln_g = (const float*)d_in[7];
    const float* ln_b = (const float*)d_in[8];
    const float* Wo   = (const float*)d_in[9];
    const float* bo   = (const float*)d_in[10];
    const float* set_w      = (const float*)d_in[11];
    const float* pos_phases = (const float*)d_in[12];
    const float* pos_weight = (const float*)d_in[13];
    const float* Wg1  = (const float*)d_in[14];
    const float* bg1  = (const float*)d_in[15];
    const float* Wg2  = (const float*)d_in[16];
    const float* bg2  = (const float*)d_in[17];
    float* out = (float*)d_out;

    // workspace: fp32 region then bf16 region, ~25.4 MB total
    float* ws   = (float*)d_ws;
    float* Y    = ws;                               // 2048*896
    float* P    = Y  + (size_t)2048*YN;             // 2*32*64*512
    float* T_   = P  + (size_t)BB*NCHUNK*NCH*512;   // 2048*512
    float* aB   = T_ + (size_t)2048*512;            // 2048*64
    float* RB   = aB + (size_t)2048*NCH;            // 2048*64
    float* bcat = RB + (size_t)2048*NCH;            // 1408
    unsigned short* Wb = (unsigned short*)(bcat + NW);      // 1408*512 bf16
    unsigned short* xb = Wb + (size_t)NW*512;               // 2048*512 bf16
    unsigned short* Tn = xb + (size_t)2048*512;             // 2048*512 bf16

    k_prep<<<dim3(NW), 128, 0, stream>>>(Wv,Wg1,Wk,Wq,Wo, bv,bg1,bk,bq,bo, Wb, bcat);
    k_xb<<<dim3(2048*512/(256*4)), 256, 0, stream>>>(x, xb);
    kg1<<<dim3(2048/64, YN/64), 256, 0, stream>>>(xb, Wb, bcat, Y);
    k_act<<<dim3(BB*LL/8), 256, 0, stream>>>(Y, Wg2, bg2, set_w, pos_phases, pos_weight, aB, RB);
    k2a_chunksum<<<dim3(NCHUNK, BB, 4), 128, 0, stream>>>(Y, aB, P);
    k2b_prefix<<<dim3(NCH, BB, 4), 128, 0, stream>>>(P);
    k2c_scan<<<dim3(NCHUNK, BB, 4), 128, 0, stream>>>(Y, aB, RB, P, T_);
    k_ln<<<dim3(2048/4), 256, 0, stream>>>(T_, ln_g, ln_b, Tn);
    kg2<<<dim3(2048/64, 512/64), 256, 0, stream>>>(Tn, Wb, bcat, x, out);
}

// Round 4
// 134.549 us; speedup vs baseline: 2.2189x; 1.2420x over previous
//
#include <hip/hip_runtime.h>
#include <math.h>

#define PI_F 3.14159265358979323846f
#define BB 2
#define LL 1024
#define NCH 64
#define CHUNK 32
#define NCHUNK (LL/CHUNK)
#define NW 1408          // Wb rows: 512 Wv | 256 Wg1 | 16 Wk | 16 Wq | 96 pad0 | 512 Wo
#define YH 384           // Yh cols: 256 h | 16 kp | 16 qp | 96 pad

typedef __attribute__((ext_vector_type(8))) short short8;
typedef __attribute__((ext_vector_type(4))) float floatx4;
typedef const __attribute__((address_space(1))) unsigned int cgu32;
typedef __attribute__((address_space(3))) unsigned int lu32;

__device__ __forceinline__ unsigned short f2bf(float f){
    unsigned u = __float_as_uint(f);
    unsigned r = (u + 0x7fff + ((u >> 16) & 1)) >> 16;   // RNE
    return (unsigned short)r;
}

// ---- prep: weights -> bf16 Wb[n][k], bcat; x -> bf16 xb ----
__global__ __launch_bounds__(128) void k_prep(
    const float* __restrict__ Wv, const float* __restrict__ Wg1,
    const float* __restrict__ Wk, const float* __restrict__ Wq,
    const float* __restrict__ Wo,
    const float* __restrict__ bv, const float* __restrict__ bg1,
    const float* __restrict__ bk, const float* __restrict__ bq,
    const float* __restrict__ bo, const float* __restrict__ x,
    unsigned short* __restrict__ Wb, float* __restrict__ bcat,
    unsigned short* __restrict__ xb)
{
    const int bid = blockIdx.x, tid = threadIdx.x;
    if (bid < NW){
        const int n = bid;
        const float* src = (n<512) ? Wv  + (size_t)n*512
                         : (n<768) ? Wg1 + (size_t)(n-512)*512
                         : (n<784) ? Wk  + (size_t)(n-768)*512
                         : (n<800) ? Wq  + (size_t)(n-784)*512
                         : (n<896) ? (const float*)0
                                   : Wo  + (size_t)(n-896)*512;
        float4 v = make_float4(0.f,0.f,0.f,0.f);
        if (src) v = ((const float4*)src)[tid];
        ushort4 o; o.x=f2bf(v.x); o.y=f2bf(v.y); o.z=f2bf(v.z); o.w=f2bf(v.w);
        ((ushort4*)(Wb + (size_t)n*512))[tid] = o;
        if (tid == 0)
            bcat[n] = (n<512)?bv[n] : (n<768)?bg1[n-512] : (n<784)?bk[n-768]
                    : (n<800)?bq[n-784] : (n<896)?0.f : bo[n-896];
    } else {
        const size_t i = (size_t)(bid - NW)*128 + tid;    // float4 index
        float4 v = ((const float4*)x)[i];
        ushort4 o; o.x=f2bf(v.x); o.y=f2bf(v.y); o.z=f2bf(v.z); o.w=f2bf(v.w);
        ((ushort4*)xb)[i] = o;
    }
}

// ---- MFMA 64x64x512 tile core (verified round 3) ----
__device__ __forceinline__ void gemm64x64(
    const unsigned short* Ag, const unsigned short* Bg,
    short* As, short* Bs, int tid, floatx4 acc[2][2])
{
    const int lane = tid & 63, w = tid >> 6;
    const int wm = w & 1, wn = w >> 1;
    const int q = lane >> 4, m15 = lane & 15;
    for (int kt = 0; kt < 512; kt += 64) {
        __syncthreads();
        #pragma unroll
        for (int i = 0; i < 2; ++i) {
            const int rowbase = (w*2 + i) * 8;
            const int r  = rowbase + (lane >> 3);
            const int gb = (lane & 7) ^ (r & 7);
            const unsigned short* ga  = Ag + (size_t)r*512 + kt + gb*8;
            const unsigned short* gbp = Bg + (size_t)r*512 + kt + gb*8;
            __builtin_amdgcn_global_load_lds((cgu32*)(const void*)ga,
                                             (lu32*)(As + rowbase*64), 16, 0, 0);
            __builtin_amdgcn_global_load_lds((cgu32*)(const void*)gbp,
                                             (lu32*)(Bs + rowbase*64), 16, 0, 0);
        }
        __syncthreads();
        #pragma unroll
        for (int k32 = 0; k32 < 64; k32 += 32) {
            short8 af[2], bf[2];
            #pragma unroll
            for (int t = 0; t < 2; ++t) {
                const int ra  = 32*wm + 16*t + m15;
                const int sba = ((k32>>3) + q) ^ (ra & 7);
                af[t] = *(const short8*)(As + ra*64 + sba*8);
                const int rb  = 32*wn + 16*t + m15;
                const int sbb = ((k32>>3) + q) ^ (rb & 7);
                bf[t] = *(const short8*)(Bs + rb*64 + sbb*8);
            }
            #pragma unroll
            for (int mt = 0; mt < 2; ++mt)
                #pragma unroll
                for (int nt = 0; nt < 2; ++nt)
                    acc[mt][nt] = __builtin_amdgcn_mfma_f32_16x16x32_bf16(
                        af[mt], bf[nt], acc[mt][nt], 0, 0, 0);
        }
    }
}

// ---- GEMM1: xb @ Wb[0:896]^T; n<512 -> Vt bf16 [b][d][l], n>=512 -> Yh fp32 ----
__global__ __launch_bounds__(256) void kg1(
    const unsigned short* __restrict__ xb, const unsigned short* __restrict__ Wb,
    const float* __restrict__ bcat, unsigned short* __restrict__ Vt,
    float* __restrict__ Yh)
{
    __shared__ short As[64*64], Bs[64*64];
    const int tid = threadIdx.x;
    const int row0 = blockIdx.x*64, n0 = blockIdx.y*64;
    floatx4 acc[2][2];
    #pragma unroll
    for (int mt=0;mt<2;++mt)
        #pragma unroll
        for (int nt=0;nt<2;++nt) acc[mt][nt] = (floatx4){0.f,0.f,0.f,0.f};
    gemm64x64(xb + (size_t)row0*512, Wb + (size_t)n0*512, As, Bs, tid, acc);
    const int lane = tid & 63, w = tid >> 6;
    const int wm = w & 1, wn = w >> 1, q = lane >> 4, m15 = lane & 15;
    if (n0 < 512){
        const int b = row0 >> 10, lb = row0 & 1023;
        #pragma unroll
        for (int mt=0;mt<2;++mt)
            #pragma unroll
            for (int nt=0;nt<2;++nt){
                const int d = n0 + 32*wn + 16*nt + m15;
                const float bb = bcat[d];
                const int l0 = lb + 32*wm + 16*mt + q*4;
                ushort4 o;
                o.x = f2bf(acc[mt][nt][0] + bb);
                o.y = f2bf(acc[mt][nt][1] + bb);
                o.z = f2bf(acc[mt][nt][2] + bb);
                o.w = f2bf(acc[mt][nt][3] + bb);
                *(ushort4*)(Vt + ((size_t)(b*512 + d))*1024 + l0) = o;
            }
    } else {
        #pragma unroll
        for (int mt=0;mt<2;++mt)
            #pragma unroll
            for (int nt=0;nt<2;++nt){
                const int n = n0 + 32*wn + 16*nt + m15;
                const float bb = bcat[n];
                #pragma unroll
                for (int reg=0;reg<4;++reg){
                    const int m = row0 + 32*wm + 16*mt + q*4 + reg;
                    Yh[(size_t)m*YH + (n-512)] = acc[mt][nt][reg] + bb;
                }
            }
    }
}

// ---- activations -> bf16 ab[l][64], Rb[l][64], aT[b][k][l] ----
__global__ __launch_bounds__(256) void k_act(
    const float* __restrict__ Yh, const float* __restrict__ Wg2,
    const float* __restrict__ bg2, const float* __restrict__ set_w,
    const float* __restrict__ pos_phases, const float* __restrict__ pos_weight,
    unsigned short* __restrict__ ab, unsigned short* __restrict__ Rb,
    unsigned short* __restrict__ aT)
{
    const int tid = threadIdx.x, lane = tid & 63, w = tid >> 6;
    const int row0 = blockIdx.x * 8;
    float s0=set_w[0], s1=set_w[1], s2=set_w[2], s3=set_w[3];
    float m = fmaxf(fmaxf(s0,s1), fmaxf(s2,s3));
    float e0=expf(s0-m), e1=expf(s1-m), e2=expf(s2-m), e3=expf(s3-m);
    float esum = e0+e1+e2+e3;
    float spw = 1.f/(1.f+expf(-pos_weight[0]));
    float b2 = bg2[0];
    #pragma unroll
    for (int rr=0;rr<2;++rr){
        int row = row0 + w + 4*rr;
        const float* yrow = Yh + (size_t)row*YH;
        float hs = 0.f;
        #pragma unroll
        for (int i=0;i<4;++i){
            float hv = yrow[lane + 64*i];
            float ge = 0.5f*hv*(1.f + erff(hv*0.70710678118f));
            hs += ge * Wg2[lane + 64*i];
        }
        #pragma unroll
        for (int off=32; off; off>>=1) hs += __shfl_xor(hs, off, 64);
        float g = 1.f/(1.f+expf(-(hs + b2)));
        if (lane < 16){
            int j = lane;
            int l = row & (LL-1);
            int b = row >> 10;
            float kang = PI_F*tanhf(yrow[256 + j]);
            float qang = PI_F*tanhf(yrow[272 + j]);
            float wsm = (j<4?e0: j<8?e1: j<12?e2: e3) / esum;
            float rnorm = 1.f/(2.f*sqrtf((float)(l+1)));
            float av[4], rv[4];
            av[0] = cosf(kang); av[1] = sinf(kang);
            float cw = g*wsm*rnorm;
            rv[0] = cw*cosf(qang); rv[1] = cw*sinf(qang);
            float ph = pos_phases[(size_t)l*16 + j];
            float pc = cosf(ph), ps = sinf(ph);
            av[2] = pc; av[3] = ps;
            float cp = (1.f-g)*spw*rnorm;
            rv[2] = cp*pc; rv[3] = cp*ps;
            unsigned short* arow = ab + (size_t)row*NCH;
            unsigned short* Rrow = Rb + (size_t)row*NCH;
            #pragma unroll
            for (int t=0;t<4;++t){
                arow[16*t + j] = f2bf(av[t]);
                Rrow[16*t + j] = f2bf(rv[t]);
                aT[((size_t)b*NCH + 16*t + j)*1024 + l] = f2bf(av[t]);
            }
        }
    }
}

// ---- k2a (MFMA): P[b][c][d][k] = sum_{l in chunk} a[k][l] * V[l][d] ----
__global__ __launch_bounds__(256) void k2a_chunksum(
    const unsigned short* __restrict__ aT, const unsigned short* __restrict__ Vt,
    float* __restrict__ P)
{
    const int c = blockIdx.x, b = blockIdx.y, z = blockIdx.z;
    const int tid = threadIdx.x, lane = tid & 63, w = tid >> 6;
    const int q = lane >> 4, m15 = lane & 15;
    short8 af[4];
    #pragma unroll
    for (int mt=0;mt<4;++mt)
        af[mt] = *(const short8*)(aT + ((size_t)b*NCH + 16*mt + m15)*1024 + c*32 + q*8);
    floatx4 acc[4][4];
    #pragma unroll
    for (int mt=0;mt<4;++mt)
        #pragma unroll
        for (int nt=0;nt<4;++nt) acc[mt][nt] = (floatx4){0.f,0.f,0.f,0.f};
    #pragma unroll
    for (int nt=0;nt<4;++nt){
        const int d = z*256 + w*64 + 16*nt + m15;
        short8 bf = *(const short8*)(Vt + ((size_t)(b*512 + d))*1024 + c*32 + q*8);
        #pragma unroll
        for (int mt=0;mt<4;++mt)
            acc[mt][nt] = __builtin_amdgcn_mfma_f32_16x16x32_bf16(af[mt], bf, acc[mt][nt], 0,0,0);
    }
    float* Pc = P + ((size_t)(b*NCHUNK + c))*512*NCH;
    #pragma unroll
    for (int mt=0;mt<4;++mt)
        #pragma unroll
        for (int nt=0;nt<4;++nt){
            const int d = z*256 + w*64 + 16*nt + m15;
            const int ch0 = 16*mt + q*4;
            *(floatx4*)(Pc + (size_t)d*NCH + ch0) = acc[mt][nt];
        }
}

// ---- k2b: exclusive prefix over chunks; emit bf16 S0t[b][c][d][k] ----
__global__ __launch_bounds__(256) void k2b_prefix(
    const float* __restrict__ P, unsigned short* __restrict__ S0t)
{
    const int b = blockIdx.y;
    const size_t idx = (size_t)blockIdx.x*256 + threadIdx.x;   // over 512*64
    float run = 0.f;
    for (int c=0;c<NCHUNK;++c){
        const size_t o = ((size_t)(b*NCHUNK + c))*512*NCH + idx;
        float v = P[o];
        S0t[o] = f2bf(run);
        run += v;
    }
}

// ---- k2c (MFMA): T = tril(R a^T) @ V + R @ S0, then LN -> Tn bf16 ----
__global__ __launch_bounds__(256) void k2c_scan(
    const unsigned short* __restrict__ ab, const unsigned short* __restrict__ Rb,
    const unsigned short* __restrict__ Vt, const unsigned short* __restrict__ S0t,
    const float* __restrict__ ln_g, const float* __restrict__ ln_b,
    unsigned short* __restrict__ Tn)
{
    __shared__ short Msh[32*32];
    __shared__ float Tsh[32*512];
    const int c = blockIdx.x, b = blockIdx.y;
    const int tid = threadIdx.x, lane = tid & 63, w = tid >> 6;
    const int q = lane >> 4, m15 = lane & 15;
    const int grow = b*1024 + c*32;

    if (w == 0){                       // wave 0 computes M = tril(R @ a^T)
        floatx4 mcc[2][2];
        #pragma unroll
        for (int mt=0;mt<2;++mt)
            #pragma unroll
            for (int nt=0;nt<2;++nt) mcc[mt][nt] = (floatx4){0.f,0.f,0.f,0.f};
        #pragma unroll
        for (int ks=0;ks<2;++ks){
            short8 ra[2], bb[2];
            #pragma unroll
            for (int t=0;t<2;++t){
                ra[t] = *(const short8*)(Rb + (size_t)(grow + 16*t + m15)*NCH + ks*32 + q*8);
                bb[t] = *(const short8*)(ab + (size_t)(grow + 16*t + m15)*NCH + ks*32 + q*8);
            }
            #pragma unroll
            for (int mt=0;mt<2;++mt)
                #pragma unroll
                for (int nt=0;nt<2;++nt)
                    mcc[mt][nt] = __builtin_amdgcn_mfma_f32_16x16x32_bf16(
                        ra[mt], bb[nt], mcc[mt][nt], 0,0,0);
        }
        #pragma unroll
        for (int mt=0;mt<2;++mt)
            #pragma unroll
            for (int nt=0;nt<2;++nt){
                const int nl = 16*nt + m15;
                #pragma unroll
                for (int reg=0;reg<4;++reg){
                    const int ml = 16*mt + q*4 + reg;
                    Msh[ml*32 + nl] = (nl <= ml) ? (short)f2bf(mcc[mt][nt][reg]) : (short)0;
                }
            }
    }
    __syncthreads();

    short8 a1[2], a2[2][2];
    #pragma unroll
    for (int mt=0;mt<2;++mt){
        a1[mt] = *(const short8*)(Msh + (16*mt + m15)*32 + q*8);
        #pragma unroll
        for (int ks=0;ks<2;++ks)
            a2[ks][mt] = *(const short8*)(Rb + (size_t)(grow + 16*mt + m15)*NCH + ks*32 + q*8);
    }
    floatx4 acc[2][8];
    #pragma unroll
    for (int mt=0;mt<2;++mt)
        #pragma unroll
        for (int nt=0;nt<8;++nt) acc[mt][nt] = (floatx4){0.f,0.f,0.f,0.f};
    const unsigned short* S0c = S0t + ((size_t)(b*NCHUNK + c))*512*NCH;
    #pragma unroll
    for (int nt=0;nt<8;++nt){
        const int d = w*128 + 16*nt + m15;
        short8 b1 = *(const short8*)(Vt + ((size_t)(b*512 + d))*1024 + c*32 + q*8);
        #pragma unroll
        for (int mt=0;mt<2;++mt)
            acc[mt][nt] = __builtin_amdgcn_mfma_f32_16x16x32_bf16(a1[mt], b1, acc[mt][nt], 0,0,0);
        #pragma unroll
        for (int ks=0;ks<2;++ks){
            short8 b2 = *(const short8*)(S0c + (size_t)d*NCH + ks*32 + q*8);
            #pragma unroll
            for (int mt=0;mt<2;++mt)
                acc[mt][nt] = __builtin_amdgcn_mfma_f32_16x16x32_bf16(a2[ks][mt], b2, acc[mt][nt], 0,0,0);
        }
    }
    #pragma unroll
    for (int mt=0;mt<2;++mt)
        #pragma unroll
        for (int nt=0;nt<8;++nt){
            const int d = w*128 + 16*nt + m15;
            #pragma unroll
            for (int reg=0;reg<4;++reg)
                Tsh[(16*mt + q*4 + reg)*512 + d] = acc[mt][nt][reg];
        }
    __syncthreads();

    // LN per row (wave handles 8 rows), write Tn bf16 row-major
    #pragma unroll
    for (int i=0;i<8;++i){
        const int r = w*8 + i;
        float s=0.f, sq=0.f;
        #pragma unroll
        for (int t=0;t<8;++t){
            float v = Tsh[r*512 + lane + 64*t];
            s += v; sq += v*v;
        }
        #pragma unroll
        for (int off=32; off; off>>=1){
            s += __shfl_xor(s, off, 64); sq += __shfl_xor(sq, off, 64);
        }
        float mu  = s*(1.f/512.f);
        float var = sq*(1.f/512.f) - mu*mu;
        float rsd = rsqrtf(var + 1e-5f);
        unsigned short* trow = Tn + (size_t)(grow + r)*512;
        #pragma unroll
        for (int t=0;t<8;++t){
            const int d = lane + 64*t;
            float v = (Tsh[r*512 + d] - mu)*rsd*ln_g[d] + ln_b[d];
            trow[d] = f2bf(v);
        }
    }
}

// ---- GEMM2: out = x + Tn @ Wo^T + bo ----
__global__ __launch_bounds__(256) void kg2(
    const unsigned short* __restrict__ Tn, const unsigned short* __restrict__ Wb,
    const float* __restrict__ bcat, const float* __restrict__ x,
    float* __restrict__ out)
{
    __shared__ short As[64*64], Bs[64*64];
    const int tid = threadIdx.x;
    const int row0 = blockIdx.x*64, n0 = blockIdx.y*64;
    floatx4 acc[2][2];
    #pragma unroll
    for (int mt=0;mt<2;++mt)
        #pragma unroll
        for (int nt=0;nt<2;++nt) acc[mt][nt] = (floatx4){0.f,0.f,0.f,0.f};
    gemm64x64(Tn + (size_t)row0*512, Wb + (size_t)(896+n0)*512, As, Bs, tid, acc);
    const int lane = tid & 63, w = tid >> 6;
    const int wm = w & 1, wn = w >> 1, q = lane >> 4, m15 = lane & 15;
    #pragma unroll
    for (int mt=0;mt<2;++mt)
        #pragma unroll
        for (int nt=0;nt<2;++nt){
            const int n = n0 + 32*wn + 16*nt + m15;
            const float bb = bcat[896 + n];
            #pragma unroll
            for (int reg=0;reg<4;++reg){
                const int m = row0 + 32*wm + 16*mt + q*4 + reg;
                out[(size_t)m*512 + n] = x[(size_t)m*512 + n] + acc[mt][nt][reg] + bb;
            }
        }
}

extern "C" void kernel_launch(void* const* d_in, const int* in_sizes, int n_in,
                              void* d_out, int out_size, void* d_ws, size_t ws_size,
                              hipStream_t stream) {
    const float* x    = (const float*)d_in[0];
    const float* Wk   = (const float*)d_in[1];
    const float* bk   = (const float*)d_in[2];
    const float* Wq   = (const float*)d_in[3];
    const float* bq   = (const float*)d_in[4];
    const float* Wv   = (const float*)d_in[5];
    const float* bv   = (const float*)d_in[6];
    const float* ln_g = (const float*)d_in[7];
    const float* ln_b = (const float*)d_in[8];
    const float* Wo   = (const float*)d_in[9];
    const float* bo   = (const float*)d_in[10];
    const float* set_w      = (const float*)d_in[11];
    const float* pos_phases = (const float*)d_in[12];
    const float* pos_weight = (const float*)d_in[13];
    const float* Wg1  = (const float*)d_in[14];
    const float* bg1  = (const float*)d_in[15];
    const float* Wg2  = (const float*)d_in[16];
    const float* bg2  = (const float*)d_in[17];
    float* out = (float*)d_out;

    // workspace: fp32 region, then bf16 region (~24 MB)
    float* ws   = (float*)d_ws;
    float* Yh   = ws;                                     // 2048*384
    float* P    = Yh + (size_t)2048*YH;                   // 2*32*512*64
    float* bcat = P  + (size_t)BB*NCHUNK*512*NCH;         // 1408
    unsigned short* Wb  = (unsigned short*)(bcat + NW);   // 1408*512
    unsigned short* xb  = Wb  + (size_t)NW*512;           // 2048*512
    unsigned short* Vt  = xb  + (size_t)2048*512;         // 2*512*1024
    unsigned short* ab  = Vt  + (size_t)BB*512*1024;      // 2048*64
    unsigned short* Rb  = ab  + (size_t)2048*NCH;         // 2048*64
    unsigned short* aT  = Rb  + (size_t)2048*NCH;         // 2*64*1024
    unsigned short* S0t = aT  + (size_t)BB*NCH*1024;      // 2*32*512*64
    unsigned short* Tn  = S0t + (size_t)BB*NCHUNK*512*NCH;// 2048*512

    k_prep<<<dim3(NW + 2048), 128, 0, stream>>>(
        Wv,Wg1,Wk,Wq,Wo, bv,bg1,bk,bq,bo, x, Wb, bcat, xb);
    kg1<<<dim3(2048/64, 14), 256, 0, stream>>>(xb, Wb, bcat, Vt, Yh);
    k_act<<<dim3(2048/8), 256, 0, stream>>>(
        Yh, Wg2, bg2, set_w, pos_phases, pos_weight, ab, Rb, aT);
    k2a_chunksum<<<dim3(NCHUNK, BB, 2), 256, 0, stream>>>(aT, Vt, P);
    k2b_prefix<<<dim3(512*NCH/256, BB), 256, 0, stream>>>(P, S0t);
    k2c_scan<<<dim3(NCHUNK, BB), 256, 0, stream>>>(ab, Rb, Vt, S0t, ln_g, ln_b, Tn);
    kg2<<<dim3(2048/64, 512/64), 256, 0, stream>>>(Tn, Wb, bcat, x, out);
}